// Round 6
// baseline (2483.736 us; speedup 1.0000x reference)
//
#include <hip/hip_runtime.h>
#include <hip/hip_fp16.h>

#define BB 16
#define NN 1024
#define DD 256

typedef _Float16 h8 __attribute__((ext_vector_type(8)));
typedef _Float16 hv4 __attribute__((ext_vector_type(4)));
typedef float f32x4 __attribute__((ext_vector_type(4)));
typedef float f32x2 __attribute__((ext_vector_type(2)));

#if __has_builtin(__builtin_amdgcn_exp2f)
#define EXP2F(x) __builtin_amdgcn_exp2f(x)
#else
#define EXP2F(x) exp2f(x)
#endif
#if __has_builtin(__builtin_amdgcn_logf)
#define LOG2F(x) __builtin_amdgcn_logf(x)
#else
#define LOG2F(x) log2f(x)
#endif

// log2-domain: A2s = -100*log2e*relu(1-S) - CPOS2*|i-j|   (pos prior folded in, fp16)
constexpr float K_A2  = -144.26950408889634f;                 // -100*log2(e)
constexpr float CPOS2 = (float)(0.2 * 1.4426950408889634 / 1023.0);
constexpr float C1    = 0.06931471805599453f;                 // ln2/10 : C_content = -C1*A2content
constexpr float BASE2 = -10.0f;                               // log2(1/1024 + 1e-12)

// padded LDS index: stride-9 pattern kills the 16-way bank conflicts of stride-8
#define PIDX(i) ((i) + ((i) >> 3))

__device__ __forceinline__ unsigned f2u(float x) { return __builtin_bit_cast(unsigned, x); }
__device__ __forceinline__ float u2f(unsigned x) { return __builtin_bit_cast(float, x); }

__device__ __forceinline__ float waveReduceSum(float v) {
#pragma unroll
  for (int o = 32; o; o >>= 1) v += __shfl_xor(v, o);
  return v;
}

// Pinned 16-byte load: inline asm so the compiler CANNOT rematerialize (re-load)
// the value inside the sinkhorn loop. Waitcnt embedded -> result valid on return.
__device__ __forceinline__ h8 lda16(const _Float16* p) {
  f32x4 r;
  asm volatile("global_load_dwordx4 %0, %1, off\n\ts_waitcnt vmcnt(0)"
               : "=v"(r) : "v"(p) : "memory");
  return __builtin_bit_cast(h8, r);
}

// Coherent (cache-bypassing) 16B load for the {value,epoch} pair polling.
__device__ __forceinline__ f32x4 ld4_cv(const float* p) {
  f32x4 r;
  asm volatile("global_load_dwordx4 %0, %1, off sc0 sc1\n\ts_waitcnt vmcnt(0)"
               : "=v"(r) : "v"(p) : "memory");
  return r;
}

// ---------------- K1: normalize rows of X and Y -> fp16 ----------------
__global__ __launch_bounds__(256) void normalize_kernel(
    const float* __restrict__ X, const float* __restrict__ Y,
    _Float16* __restrict__ Xh, _Float16* __restrict__ Yh) {
  int wave = threadIdx.x >> 6;
  int lane = threadIdx.x & 63;
  int row = blockIdx.x * 4 + wave;           // 0 .. 2*BB*NN-1
  const float* src;
  _Float16* dst;
  if (row < BB * NN) { src = X + (size_t)row * DD; dst = Xh + (size_t)row * DD; }
  else { int r2 = row - BB * NN; src = Y + (size_t)r2 * DD; dst = Yh + (size_t)r2 * DD; }
  float4 v = *(const float4*)(src + lane * 4);
  float ss = v.x * v.x + v.y * v.y + v.z * v.z + v.w * v.w;
  ss = waveReduceSum(ss);
  float sc = 1.0f / fmaxf(sqrtf(ss), 1e-12f);
  hv4 hv;
  hv[0] = (_Float16)(v.x * sc); hv[1] = (_Float16)(v.y * sc);
  hv[2] = (_Float16)(v.z * sc); hv[3] = (_Float16)(v.w * sc);
  *(hv4*)(dst + lane * 4) = hv;
}

// ---------------- K2: S = Ah . Bh^T per batch, write A2s (content+pos, fp16) ----
__global__ __launch_bounds__(256) void gemm_a2_kernel(
    const _Float16* __restrict__ Ah, const _Float16* __restrict__ Bh,
    _Float16* __restrict__ Out) {
  const int b = blockIdx.z;
  const int I0 = blockIdx.y * 128;
  const int J0 = blockIdx.x * 128;
  const int lane = threadIdx.x & 63;
  const int wave = threadIdx.x >> 6;
  const int m = lane & 15, quad = lane >> 4;
  const _Float16* Abase = Ah + ((size_t)b * NN + I0 + wave * 32) * DD;
  const _Float16* Bbase = Bh + ((size_t)b * NN + J0) * DD;
  f32x4 acc[2][8] = {};
  for (int k0 = 0; k0 < DD; k0 += 32) {
    int koff = k0 + quad * 8;
    h8 a0 = *(const h8*)(Abase + (size_t)m * DD + koff);
    h8 a1 = *(const h8*)(Abase + (size_t)(m + 16) * DD + koff);
#pragma unroll
    for (int t = 0; t < 8; ++t) {
      h8 bf = *(const h8*)(Bbase + (size_t)(t * 16 + m) * DD + koff);
      acc[0][t] = __builtin_amdgcn_mfma_f32_16x16x32_f16(a0, bf, acc[0][t], 0, 0, 0);
      acc[1][t] = __builtin_amdgcn_mfma_f32_16x16x32_f16(a1, bf, acc[1][t], 0, 0, 0);
    }
  }
  _Float16* Ob = Out + ((size_t)b * NN + I0 + wave * 32) * NN + J0;
#pragma unroll
  for (int a = 0; a < 2; ++a)
#pragma unroll
    for (int t = 0; t < 8; ++t)
#pragma unroll
      for (int r = 0; r < 4; ++r) {
        int row = a * 16 + quad * 4 + r;
        int col = t * 16 + m;
        float s = acc[a][t][r];
        float ri = (float)(I0 + wave * 32 + row);
        float ci = (float)(J0 + col);
        Ob[(size_t)row * NN + col] =
            (_Float16)(K_A2 * fmaxf(1.0f - s, 0.0f) - CPOS2 * fabsf(ri - ci));
      }
}

// ---------------- Sinkhorn: dataflow-synchronized persistent kernel ----------------
// No barrier at all. Duals are published as {f32 value, u32 epoch} 8-byte pairs
// (atomic visibility at 8B). Consumers poll the pairs themselves until the epoch
// arrives. Anti-overwrite is guaranteed by dataflow: a block can only produce
// epoch e+1 after consuming ALL of epoch e's counterpart vector, which requires
// every other block to have consumed this block's epoch-e output first.

// stage 1024 pairs (8 KB) -> LDS values; thread t owns pairs 2t, 2t+1.
__device__ __forceinline__ void stagePairs(float* lds, const float* __restrict__ pairs,
                                           int t, unsigned target) {
  const float* src = pairs + 4 * t;   // 2 pairs = 4 floats
  f32x4 v = ld4_cv(src);
  while (f2u(v[1]) < target || f2u(v[3]) < target) {
    __builtin_amdgcn_s_sleep(2);
    v = ld4_cv(src);
  }
  int i = 2 * t;
  lds[PIDX(i)] = v[0];
  lds[PIDX(i + 1)] = v[2];
}

// lanes 0..7 publish the wave's 8 row-results (values are wave-uniform after
// the reductions) as {value, tag} pairs with one 8B coherent store each.
__device__ __forceinline__ void storeRows(float* pairs, int r0, const float (&rs)[8],
                                          unsigned tag, int lane) {
  if (lane < 8) {
    float v = rs[0];
    v = lane == 1 ? rs[1] : v;
    v = lane == 2 ? rs[2] : v;
    v = lane == 3 ? rs[3] : v;
    v = lane == 4 ? rs[4] : v;
    v = lane == 5 ? rs[5] : v;
    v = lane == 6 ? rs[6] : v;
    v = lane == 7 ? rs[7] : v;
    f32x2 q;
    q[0] = v;
    q[1] = u2f(tag);
    float* p = pairs + (size_t)(r0 + lane) * 2;
    asm volatile("global_store_dwordx2 %0, %1, off sc0 sc1" :: "v"(p), "v"(q)
                 : "memory");
  }
}

__device__ __forceinline__ void ldsVec16p(const float* lds, int j0, float (&out)[16]) {
#pragma unroll
  for (int k = 0; k < 8; ++k) {
    out[k] = lds[PIDX(j0 + k)];
    out[8 + k] = lds[PIDX(512 + j0 + k)];
  }
}

__device__ __forceinline__ float lseRow(const h8 (&rw)[2], const float (&gv)[16]) {
  float x[16];
#pragma unroll
  for (int k = 0; k < 8; ++k) {
    x[k]     = (float)rw[0][k] + gv[k];
    x[8 + k] = (float)rw[1][k] + gv[8 + k];
  }
  float m = x[0];
#pragma unroll
  for (int k = 1; k < 16; ++k) m = fmaxf(m, x[k]);
#pragma unroll
  for (int o = 32; o; o >>= 1) m = fmaxf(m, __shfl_xor(m, o));
  float s = 0.f;
#pragma unroll
  for (int k = 0; k < 16; ++k) s += EXP2F(x[k] - m);
  s = waveReduceSum(s);
  return BASE2 - (m + LOG2F(s));
}

// grid 256 blocks x 512 thr: batch = bid&15, 16 blocks/batch. Each wave owns
// 8 rows of A2 and 8 rows of A2T pinned in VGPRs (asm loads, 128 VGPRs).
__global__ __launch_bounds__(512, 2) void sinkhorn_kernel(
    const _Float16* __restrict__ A2, const _Float16* __restrict__ A2T,
    float* __restrict__ Fp, float* __restrict__ Gp,
    float* __restrict__ Fv, float* __restrict__ Gv,
    float* __restrict__ rOut, float* __restrict__ cOut,
    float* __restrict__ LrowOut) {
  __shared__ float ldsG[NN + NN / 8];
  __shared__ float ldsF[NN + NN / 8];
  const int batch = blockIdx.x & 15;
  const int blkSub = blockIdx.x >> 4;            // 0..15
  const int t = threadIdx.x;
  const int lane = t & 63;
  const int wave = t >> 6;                       // 0..7
  const int r0 = blkSub * 64 + wave * 8;         // 8 rows per wave
  const int j0 = lane * 8;
  const _Float16* Pa = A2 + (size_t)batch * NN * NN;
  const _Float16* Pt = A2T + (size_t)batch * NN * NN;
  float* Fpb = Fp + (size_t)batch * NN * 2;
  float* Gpb = Gp + (size_t)batch * NN * 2;

  h8 ra[8][2], rt[8][2];
#pragma unroll
  for (int r = 0; r < 8; ++r) {
    const _Float16* rowA = Pa + (size_t)(r0 + r) * NN + j0;
    const _Float16* rowT = Pt + (size_t)(r0 + r) * NN + j0;
    ra[r][0] = lda16(rowA);
    ra[r][1] = lda16(rowA + 512);
    rt[r][0] = lda16(rowT);
    rt[r][1] = lda16(rowT + 512);
  }

  for (int it = 0; it < 50; ++it) {
    // stage g(epoch 2it) -> ldsG  (it=0: epoch 0 = memset zeros, instant)
    stagePairs(ldsG, Gpb, t, (unsigned)(2 * it));
    __syncthreads();
    {  // f-phase: f = lse(ra + g), publish epoch 2it+1
      float gv[16];
      ldsVec16p(ldsG, j0, gv);
      float rs[8];
#pragma unroll
      for (int r = 0; r < 8; ++r) rs[r] = lseRow(ra[r], gv);
      storeRows(Fpb, r0, rs, (unsigned)(2 * it + 1), lane);
    }
    // stage f(epoch 2it+1) -> ldsF
    stagePairs(ldsF, Fpb, t, (unsigned)(2 * it + 1));
    __syncthreads();
    {  // g-phase: g = lse(rt + f), publish epoch 2it+2
      float fv[16];
      ldsVec16p(ldsF, j0, fv);
      float rs[8];
#pragma unroll
      for (int r = 0; r < 8; ++r) rs[r] = lseRow(rt[r], fv);
      storeRows(Gpb, r0, rs, (unsigned)(2 * it + 2), lane);
    }
  }
  // final g (epoch 100) -> ldsG ; ldsF already holds final f (epoch 99)
  stagePairs(ldsG, Gpb, t, 100u);
  __syncthreads();

  // Epilogue: r_i = sum_j T, c_j = sum_i T, Lrow_i = sum_j T*C_content;
  // also dump plain-float F/G for the downstream kernels.
  float fv[16], gv[16];
  ldsVec16p(ldsF, j0, fv);
  ldsVec16p(ldsG, j0, gv);
#pragma unroll
  for (int r = 0; r < 8; ++r) {
    int i = r0 + r;
    float fi = ldsF[PIDX(i)];
    float gi = ldsG[PIDX(i)];
    float fr = (float)i;
    float sr = 0.f, sl = 0.f, sc = 0.f;
#pragma unroll
    for (int k = 0; k < 8; ++k) {
      float a2a = (float)ra[r][0][k];
      float a2b = (float)ra[r][1][k];
      float Ta = EXP2F(a2a + fi + gv[k]);
      float Tb = EXP2F(a2b + fi + gv[8 + k]);
      sr += Ta + Tb;
      float ca = a2a + CPOS2 * fabsf(fr - (float)(j0 + k));
      float cb = a2b + CPOS2 * fabsf(fr - (float)(512 + j0 + k));
      sl = fmaf(Ta, ca, sl);
      sl = fmaf(Tb, cb, sl);
      sc += EXP2F((float)rt[r][0][k] + gi + fv[k]);
      sc += EXP2F((float)rt[r][1][k] + gi + fv[8 + k]);
    }
    sr = waveReduceSum(sr);
    sl = waveReduceSum(sl);
    sc = waveReduceSum(sc);
    if (lane == 0) {
      rOut[batch * NN + i] = sr;
      cOut[batch * NN + i] = sc;
      LrowOut[batch * NN + i] = -C1 * sl;
      Fv[batch * NN + i] = fi;
      Gv[batch * NN + i] = gi;
    }
  }
}

// ---------------- K6: num = T @ Emb ; accumulate sum((Ref - num/denom)^2) ----------
__global__ __launch_bounds__(512) void bary_kernel(
    const _Float16* __restrict__ P, const float* __restrict__ rowv,
    const float* __restrict__ colv, const float* __restrict__ denom,
    const float* __restrict__ Emb, const float* __restrict__ Ref,
    float* __restrict__ baryAcc) {
  const int b = blockIdx.y;
  const int I0 = blockIdx.x * 64;
  const _Float16* Pb = P + (size_t)b * NN * NN;
  const float* rv = rowv + b * NN;
  const float* cvv = colv + b * NN;
  const float* dn = denom + b * NN;
  const float* Eb = Emb + (size_t)b * NN * DD;
  const float* Rb = Ref + (size_t)b * NN * DD;
  __shared__ float Tl[64 * 64];
  __shared__ float red[8];
  const int t = threadIdx.x;
  const int rg = t >> 8, d = t & 255;
  float acc[32];
#pragma unroll
  for (int k = 0; k < 32; ++k) acc[k] = 0.f;
  for (int ch = 0; ch < 16; ++ch) {
    __syncthreads();
    {
      int jj = t & 63;
      int jabs = ch * 64 + jj;
      float gvv = cvv[jabs];
      int ii0 = (t >> 6) * 8;
#pragma unroll
      for (int k = 0; k < 8; ++k) {
        int ii = ii0 + k;
        int iabs = I0 + ii;
        float a2f = (float)Pb[(size_t)iabs * NN + jabs];
        Tl[ii * 64 + jj] = EXP2F(a2f + rv[iabs] + gvv);
      }
    }
    __syncthreads();
    const float* Yc = Eb + (size_t)(ch * 64) * DD + d;
    for (int jg = 0; jg < 16; ++jg) {
      float y0 = Yc[(size_t)(jg * 4 + 0) * DD];
      float y1 = Yc[(size_t)(jg * 4 + 1) * DD];
      float y2 = Yc[(size_t)(jg * 4 + 2) * DD];
      float y3 = Yc[(size_t)(jg * 4 + 3) * DD];
#pragma unroll
      for (int ii = 0; ii < 32; ++ii) {
        const float4 tv = *(const float4*)&Tl[(rg * 32 + ii) * 64 + jg * 4];
        acc[ii] = fmaf(tv.x, y0, acc[ii]);
        acc[ii] = fmaf(tv.y, y1, acc[ii]);
        acc[ii] = fmaf(tv.z, y2, acc[ii]);
        acc[ii] = fmaf(tv.w, y3, acc[ii]);
      }
    }
  }
  float vs = 0.f;
#pragma unroll
  for (int ii = 0; ii < 32; ++ii) {
    int iabs = I0 + rg * 32 + ii;
    float val = Rb[(size_t)iabs * DD + d] - acc[ii] / (dn[iabs] + 1e-8f);
    vs = fmaf(val, val, vs);
  }
  vs = waveReduceSum(vs);
  int lane = t & 63, wave = t >> 6;
  if (lane == 0) red[wave] = vs;
  __syncthreads();
  if (t == 0) {
    float tot = 0.f;
    for (int w = 0; w < 8; ++w) tot += red[w];
    atomicAdd(baryAcc + b, tot);
  }
}

// ---------------- K7: partial global sums X*r, Y*c ----------------
__global__ __launch_bounds__(256) void xg_kernel(
    const float* __restrict__ X, const float* __restrict__ Y,
    const float* __restrict__ r, const float* __restrict__ c,
    float* __restrict__ xgp, float* __restrict__ ygp) {
  const int b = blockIdx.y, seg = blockIdx.x, d = threadIdx.x;
  float ax = 0.f, ay = 0.f;
  for (int ii = 0; ii < 256; ++ii) {
    int i = seg * 256 + ii;
    float rvv = r[b * NN + i];
    float cvv = c[b * NN + i];
    ax = fmaf(X[((size_t)b * NN + i) * DD + d], rvv, ax);
    ay = fmaf(Y[((size_t)b * NN + i) * DD + d], cvv, ay);
  }
  xgp[(size_t)(b * 4 + seg) * DD + d] = ax;
  ygp[(size_t)(b * 4 + seg) * DD + d] = ay;
}

// ---------------- K8: per-batch finalize ----------------
__global__ __launch_bounds__(256) void finalize_batch(
    const float* __restrict__ r, const float* __restrict__ c,
    const float* __restrict__ Lrow, const float* __restrict__ xgp,
    const float* __restrict__ ygp, const float* __restrict__ baryA,
    const float* __restrict__ baryB, float* __restrict__ lossArr) {
  const int b = blockIdx.x;
  const int t = threadIdx.x;
  __shared__ float sd[256];
  auto bsum = [&](float v) -> float {
    sd[t] = v; __syncthreads();
    for (int o = 128; o; o >>= 1) { if (t < o) sd[t] += sd[t + o]; __syncthreads(); }
    float res = sd[0]; __syncthreads();
    return res;
  };
  float vr = 0.f, vc = 0.f, vl = 0.f;
  for (int k = 0; k < 4; ++k) {
    int i = t + 256 * k;
    vr += r[b * NN + i];
    vc += c[b * NN + i];
    vl += Lrow[b * NN + i];
  }
  float sumR = bsum(vr);
  float sumC = bsum(vc);
  float Lmain = bsum(vl);
  float xg = (xgp[(size_t)(b * 4 + 0) * DD + t] + xgp[(size_t)(b * 4 + 1) * DD + t] +
              xgp[(size_t)(b * 4 + 2) * DD + t] + xgp[(size_t)(b * 4 + 3) * DD + t]) /
             (sumR + 1e-8f);
  float yg = (ygp[(size_t)(b * 4 + 0) * DD + t] + ygp[(size_t)(b * 4 + 1) * DD + t] +
              ygp[(size_t)(b * 4 + 2) * DD + t] + ygp[(size_t)(b * 4 + 3) * DD + t]) /
             (sumC + 1e-8f);
  float nx = bsum(xg * xg);
  float ny = bsum(yg * yg);
  float dt = bsum(xg * yg);
  if (t == 0) {
    float mx = fmaxf(sqrtf(nx), 1e-12f);
    float my = fmaxf(sqrtf(ny), 1e-12f);
    float cosv = dt / (mx * my);
    float lb = (baryA[b] + baryB[b]) * (1.0f / ((float)NN * (float)DD));
    lossArr[b] = Lmain + 0.5f * lb + 0.2f * (1.0f - cosv);
  }
}

__global__ void final_mean(const float* __restrict__ lossArr, float* __restrict__ out) {
  int t = threadIdx.x;
  float v = (t < BB) ? lossArr[t] : 0.f;
  v = waveReduceSum(v);
  if (t == 0) out[0] = v * (1.0f / BB);
}

// ---------------- launch ----------------
extern "C" void kernel_launch(void* const* d_in, const int* in_sizes, int n_in,
                              void* d_out, int out_size, void* d_ws, size_t ws_size,
                              hipStream_t stream) {
  const float* X = (const float*)d_in[0];
  const float* Y = (const float*)d_in[1];
  float* out = (float*)d_out;
  char* ws = (char*)d_ws;
  size_t off = 0;
  auto take = [&](size_t bytes) -> char* {
    char* p = ws + off;
    off = (off + bytes + 255) & ~(size_t)255;
    return p;
  };
  _Float16* Xh = (_Float16*)take((size_t)BB * NN * DD * 2);
  _Float16* Yh = (_Float16*)take((size_t)BB * NN * DD * 2);
  _Float16* A2 = (_Float16*)take((size_t)BB * NN * NN * 2);
  _Float16* A2T = (_Float16*)take((size_t)BB * NN * NN * 2);
  size_t zstart = off;
  float* Fp = (float*)take((size_t)BB * NN * 8);   // {value, epoch} pairs
  float* Gp = (float*)take((size_t)BB * NN * 8);
  float* baryA = (float*)take(64);
  float* baryB = (float*)take(64);
  size_t zlen = off - zstart;
  float* Fv = (float*)take((size_t)BB * NN * 4);
  float* Gv = (float*)take((size_t)BB * NN * 4);
  float* r = (float*)take((size_t)BB * NN * 4);
  float* c = (float*)take((size_t)BB * NN * 4);
  float* Lrow = (float*)take((size_t)BB * NN * 4);
  float* xgp = (float*)take((size_t)BB * 4 * DD * 4);
  float* ygp = (float*)take((size_t)BB * 4 * DD * 4);
  float* lossArr = (float*)take(64);
  (void)in_sizes; (void)n_in; (void)out_size; (void)ws_size;

  hipMemsetAsync(ws + zstart, 0, zlen, stream);

  normalize_kernel<<<dim3(2 * BB * NN / 4), dim3(256), 0, stream>>>(X, Y, Xh, Yh);
  gemm_a2_kernel<<<dim3(NN / 128, NN / 128, BB), dim3(256), 0, stream>>>(Xh, Yh, A2);
  gemm_a2_kernel<<<dim3(NN / 128, NN / 128, BB), dim3(256), 0, stream>>>(Yh, Xh, A2T);
  sinkhorn_kernel<<<dim3(256), dim3(512), 0, stream>>>(A2, A2T, Fp, Gp, Fv, Gv, r, c,
                                                       Lrow);
  bary_kernel<<<dim3(NN / 64, BB), dim3(512), 0, stream>>>(A2, Fv, Gv, r, Y, X, baryA);
  bary_kernel<<<dim3(NN / 64, BB), dim3(512), 0, stream>>>(A2T, Gv, Fv, c, X, Y, baryB);
  xg_kernel<<<dim3(4, BB), dim3(256), 0, stream>>>(X, Y, r, c, xgp, ygp);
  finalize_batch<<<dim3(BB), dim3(256), 0, stream>>>(r, c, Lrow, xgp, ygp, baryA, baryB,
                                                     lossArr);
  final_mean<<<dim3(1), dim3(64), 0, stream>>>(lossArr, out);
}